// Round 5
// baseline (182.380 us; speedup 1.0000x reference)
//
#include <hip/hip_runtime.h>
#include <math.h>

#define B_N   32768
#define SD    5
#define MD    4
#define HID   128
#define NH    64
#define NSIG  11
#define DT    0.01f

#define IDX(i, j) ((i) * ((i) + 1) / 2 + (j))

typedef __fp16 f16x2 __attribute__((ext_vector_type(2)));
typedef float  f32x4 __attribute__((ext_vector_type(4)));

#define CONST_AS __attribute__((address_space(4)))

// Force scalar (s_load) path: generic -> constant address space cast (CK idiom).
__device__ __forceinline__ f32x4 ldc4(const float* p) {
    return *(const CONST_AS f32x4*)(uintptr_t)p;
}

__device__ __forceinline__ float fexp2(float x) {
#if __has_builtin(__builtin_amdgcn_exp2f)
    return __builtin_amdgcn_exp2f(x);
#else
    return exp2f(x);
#endif
}

__device__ __forceinline__ float fexp(float x) {
    return fexp2(x * 1.4426950408889634f);
}

__device__ __forceinline__ f16x2 pkh(float a, float b) {
#if __has_builtin(__builtin_amdgcn_cvt_pkrtz)
    return __builtin_amdgcn_cvt_pkrtz(a, b);
#else
    f16x2 r; r.x = (__fp16)a; r.y = (__fp16)b; return r;
#endif
}

__device__ __forceinline__ float fdot2(f16x2 a, f16x2 b, float c) {
#if __has_builtin(__builtin_amdgcn_fdot2)
    return __builtin_amdgcn_fdot2(a, b, c, false);
#else
    return fmaf((float)a.x, (float)b.x, fmaf((float)a.y, (float)b.y, c));
#endif
}

__device__ __forceinline__ f16x2 h2(float f) {
    union { float f; f16x2 h; } u; u.f = f; return u.h;
}

// odd order-9 polynomial tanh, clamped to [-3,3]; max err ~1.6e-2 near x=2.
__device__ __forceinline__ float tpoly(float x) {
#if __has_builtin(__builtin_amdgcn_fmed3f)
    float p = __builtin_amdgcn_fmed3f(x, -3.0f, 3.0f);
#else
    float p = fminf(fmaxf(x, -3.0f), 3.0f);
#endif
    float u = p * p;
    float h = fmaf(u, 0.000412619f, -0.00901606f);
    h = fmaf(u, h, 0.07293188f);
    h = fmaf(u, h, -0.30093534f);
    h = fmaf(u, h, 0.9982018f);
    return p * h;
}

// ---- prep: pack weights as f16 pairs, one 64B row per pair of hidden units ----
// Sigma MLP, pair p (k0=2p, k1=2p+1), wpk[p][16 floats]:
//   [0..3]  = A-row k0: (W1[0][k0],W1[1][k0]) (W1[2],W1[3]) (W1[4],W1[5]) (W1[6],b1)
//   [4..7]  = A-row k1 likewise
//   [8..14] = acc j=0..6: (W2[k0][j], W2[k1][j])
// Noise MLP, pair p, wnk[p][16 floats]:
//   [0..2] = n-row k0, [3..5] = n-row k1, [6..10] = Q acc, [11..14] = R acc
__global__ void ukf_prep(const float* __restrict__ W1, const float* __restrict__ b1,
                         const float* __restrict__ W2,
                         const float* __restrict__ Wn1, const float* __restrict__ bn1,
                         const float* __restrict__ Wq, const float* __restrict__ Wr,
                         float* __restrict__ wpk, float* __restrict__ wnk) {
    const int p = threadIdx.x;
    union { f16x2 h; float f; } u;
    if (p < 64) {
        const int k0 = 2 * p, k1 = 2 * p + 1;
        float* o = wpk + p * 16;
        u.h = pkh(W1[0 * HID + k0], W1[1 * HID + k0]); o[0] = u.f;
        u.h = pkh(W1[2 * HID + k0], W1[3 * HID + k0]); o[1] = u.f;
        u.h = pkh(W1[4 * HID + k0], W1[5 * HID + k0]); o[2] = u.f;
        u.h = pkh(W1[6 * HID + k0], b1[k0]);           o[3] = u.f;
        u.h = pkh(W1[0 * HID + k1], W1[1 * HID + k1]); o[4] = u.f;
        u.h = pkh(W1[2 * HID + k1], W1[3 * HID + k1]); o[5] = u.f;
        u.h = pkh(W1[4 * HID + k1], W1[5 * HID + k1]); o[6] = u.f;
        u.h = pkh(W1[6 * HID + k1], b1[k1]);           o[7] = u.f;
#pragma unroll
        for (int j = 0; j < 7; ++j) {
            u.h = pkh(W2[k0 * 7 + j], W2[k1 * 7 + j]); o[8 + j] = u.f;
        }
        o[15] = 0.0f;
    }
    if (p < 32) {
        const int k0 = 2 * p, k1 = 2 * p + 1;
        float* o = wnk + p * 16;
        u.h = pkh(Wn1[0 * NH + k0], Wn1[1 * NH + k0]); o[0] = u.f;
        u.h = pkh(Wn1[2 * NH + k0], Wn1[3 * NH + k0]); o[1] = u.f;
        u.h = pkh(Wn1[4 * NH + k0], bn1[k0]);          o[2] = u.f;
        u.h = pkh(Wn1[0 * NH + k1], Wn1[1 * NH + k1]); o[3] = u.f;
        u.h = pkh(Wn1[2 * NH + k1], Wn1[3 * NH + k1]); o[4] = u.f;
        u.h = pkh(Wn1[4 * NH + k1], bn1[k1]);          o[5] = u.f;
#pragma unroll
        for (int j = 0; j < 5; ++j) {
            u.h = pkh(Wq[k0 * 5 + j], Wq[k1 * 5 + j]); o[6 + j] = u.f;
        }
#pragma unroll
        for (int j = 0; j < 4; ++j) {
            u.h = pkh(Wr[k0 * 4 + j], Wr[k1 * 4 + j]); o[11 + j] = u.f;
        }
        o[15] = 0.0f;
    }
}

// MLP dynamics via paired v_dot2_f32_f16 + polynomial tanh. Weight reads go
// through constant-AS scalar loads (s_load) -> zero per-lane VMEM in the loop.
__device__ __forceinline__ void dyn_eval(const float* __restrict__ wpk,
                                         const float* __restrict__ b2r,
                                         const float* __restrict__ z,
                                         float* __restrict__ out) {
    const f16x2 z0 = pkh(z[0], z[1]);
    const f16x2 z1 = pkh(z[2], z[3]);
    const f16x2 z2 = pkh(z[4], z[5]);
    const f16x2 z3 = pkh(z[6], 1.0f);
    float a0 = b2r[0], a1 = b2r[1], a2 = b2r[2], a3 = b2r[3];
    float a4 = b2r[4], a5 = b2r[5], a6 = b2r[6];
#pragma unroll 4
    for (int p = 0; p < 64; ++p) {
        const float* wrow = wpk + (p << 4);
        f32x4 wa = ldc4(wrow);
        f32x4 wb = ldc4(wrow + 4);
        f32x4 wc = ldc4(wrow + 8);
        f32x4 wd = ldc4(wrow + 12);
        float preA = fdot2(z3, h2(wa.w), fdot2(z2, h2(wa.z),
                      fdot2(z1, h2(wa.y), fdot2(z0, h2(wa.x), 0.0f))));
        float preB = fdot2(z3, h2(wb.w), fdot2(z2, h2(wb.z),
                      fdot2(z1, h2(wb.y), fdot2(z0, h2(wb.x), 0.0f))));
        f16x2 tt = pkh(tpoly(preA), tpoly(preB));
        a0 = fdot2(tt, h2(wc.x), a0);
        a1 = fdot2(tt, h2(wc.y), a1);
        a2 = fdot2(tt, h2(wc.z), a2);
        a3 = fdot2(tt, h2(wc.w), a3);
        a4 = fdot2(tt, h2(wd.x), a4);
        a5 = fdot2(tt, h2(wd.y), a5);
        a6 = fdot2(tt, h2(wd.z), a6);
    }
    out[0] = a0; out[1] = a1; out[2] = a2; out[3] = a3;
    out[4] = a4; out[5] = a5; out[6] = a6;
}

// single main kernel: block = 704 threads = 64 elements x 11 sigma points.
__global__ __launch_bounds__(704) void ukf_main(
    const float* __restrict__ Xh, const float* __restrict__ Pin,
    const float* __restrict__ Uin, const float* __restrict__ Yin,
    const float* __restrict__ b2g, const float* __restrict__ bqg,
    const float* __restrict__ brg, const float* __restrict__ Hg,
    const float* __restrict__ wpk, const float* __restrict__ wnk,
    float* __restrict__ out) {
    __shared__ float spts[64 * 55];   // [elem][sig][5]

    const int tid = threadIdx.x;
    const int e = tid / NSIG;
    const int s = tid - e * NSIG;
    const int b = blockIdx.x * 64 + e;

    float b2r[7];
#pragma unroll
    for (int j = 0; j < 7; ++j) b2r[j] = b2g[j];

    float x[SD];
#pragma unroll
    for (int i = 0; i < SD; ++i) x[i] = Xh[b * SD + i];
    const float u0 = Uin[b * 2 + 0];
    const float u1 = Uin[b * 2 + 1];

    // Cholesky of 3*P (packed lower), redundantly per sigma-thread
    float L[15];
#pragma unroll
    for (int i = 0; i < SD; ++i)
#pragma unroll
        for (int j = 0; j <= i; ++j)
            L[IDX(i, j)] = 3.0f * Pin[b * 25 + i * 5 + j];
#pragma unroll
    for (int j = 0; j < SD; ++j) {
        float d = L[IDX(j, j)];
#pragma unroll
        for (int k = 0; k < j; ++k) { float l = L[IDX(j, k)]; d = fmaf(-l, l, d); }
        d = sqrtf(d);
        L[IDX(j, j)] = d;
        float inv = 1.0f / d;
#pragma unroll
        for (int i = j + 1; i < SD; ++i) {
            float v = L[IDX(i, j)];
#pragma unroll
            for (int k = 0; k < j; ++k) v = fmaf(-L[IDX(i, k)], L[IDX(j, k)], v);
            L[IDX(i, j)] = v * inv;
        }
    }

    float z[7];
#pragma unroll
    for (int i = 0; i < SD; ++i) z[i] = x[i];
    z[5] = u0; z[6] = u1;
    {
        const int c = (s >= 6) ? (s - 6) : (s - 1);   // -1 when s==0
        const float sgn = (s >= 6) ? -1.0f : 1.0f;
#pragma unroll
        for (int cc = 0; cc < SD; ++cc) {
            if (cc == c) {
#pragma unroll
                for (int i = cc; i < SD; ++i) z[i] = fmaf(sgn, L[IDX(i, cc)], z[i]);
            }
        }
    }

    float kc[7], ks[7], zc[7];
    dyn_eval(wpk, b2r, z, kc);                         // k1
#pragma unroll
    for (int i = 0; i < 7; ++i) { ks[i] = kc[i]; zc[i] = fmaf(0.5f * DT, kc[i], z[i]); }
    dyn_eval(wpk, b2r, zc, kc);                        // k2
#pragma unroll
    for (int i = 0; i < 7; ++i) { ks[i] = fmaf(2.0f, kc[i], ks[i]); zc[i] = fmaf(0.5f * DT, kc[i], z[i]); }
    dyn_eval(wpk, b2r, zc, kc);                        // k3
#pragma unroll
    for (int i = 0; i < 7; ++i) { ks[i] = fmaf(2.0f, kc[i], ks[i]); zc[i] = fmaf(DT, kc[i], z[i]); }
    dyn_eval(wpk, b2r, zc, kc);                        // k4
#pragma unroll
    for (int i = 0; i < SD; ++i)
        spts[e * 55 + s * 5 + i] = fmaf(DT / 6.0f, ks[i] + kc[i], z[i]);

    __syncthreads();

    // ---------------- phase 2: one thread per element ----------------
    if (tid < 64) {
        const int bb = blockIdx.x * 64 + tid;

        float xp[SD], M[15];
#pragma unroll
        for (int i = 0; i < SD; ++i) xp[i] = 0.0f;
#pragma unroll
        for (int i = 0; i < 15; ++i) M[i] = 0.0f;
#pragma unroll
        for (int si = 0; si < NSIG; ++si) {
            const float w = (si == 0) ? (-2.0f / 3.0f) : (1.0f / 6.0f);
            float p[SD];
#pragma unroll
            for (int i = 0; i < SD; ++i) p[i] = spts[tid * 55 + si * 5 + i];
#pragma unroll
            for (int i = 0; i < SD; ++i) xp[i] = fmaf(w, p[i], xp[i]);
#pragma unroll
            for (int i = 0; i < SD; ++i)
#pragma unroll
                for (int j = 0; j <= i; ++j)
                    M[IDX(i, j)] = fmaf(w * p[i], p[j], M[IDX(i, j)]);
        }
        float Pp[15];
#pragma unroll
        for (int i = 0; i < SD; ++i)
#pragma unroll
            for (int j = 0; j <= i; ++j)
                Pp[IDX(i, j)] = fmaf(-xp[i], xp[j], M[IDX(i, j)]);

        // noise MLP on original X_hat (paired dot2 + poly tanh, scalar loads)
        float xh[SD];
#pragma unroll
        for (int i = 0; i < SD; ++i) xh[i] = Xh[bb * SD + i];
        const f16x2 x0 = pkh(xh[0], xh[1]);
        const f16x2 x1 = pkh(xh[2], xh[3]);
        const f16x2 x2 = pkh(xh[4], 1.0f);
        float gq[5] = {0.f, 0.f, 0.f, 0.f, 0.f};
        float gr[4] = {0.f, 0.f, 0.f, 0.f};
#pragma unroll 4
        for (int p = 0; p < 32; ++p) {
            const float* wrow = wnk + (p << 4);
            f32x4 wa = ldc4(wrow);
            f32x4 wb = ldc4(wrow + 4);
            f32x4 wc = ldc4(wrow + 8);
            f32x4 wd = ldc4(wrow + 12);
            float preA = fdot2(x2, h2(wa.z), fdot2(x1, h2(wa.y), fdot2(x0, h2(wa.x), 0.0f)));
            float preB = fdot2(x2, h2(wb.y), fdot2(x1, h2(wb.x), fdot2(x0, h2(wa.w), 0.0f)));
            f16x2 tt = pkh(tpoly(preA), tpoly(preB));
            gq[0] = fdot2(tt, h2(wb.z), gq[0]);
            gq[1] = fdot2(tt, h2(wb.w), gq[1]);
            gq[2] = fdot2(tt, h2(wc.x), gq[2]);
            gq[3] = fdot2(tt, h2(wc.y), gq[3]);
            gq[4] = fdot2(tt, h2(wc.z), gq[4]);
            gr[0] = fdot2(tt, h2(wc.w), gr[0]);
            gr[1] = fdot2(tt, h2(wd.x), gr[1]);
            gr[2] = fdot2(tt, h2(wd.y), gr[2]);
            gr[3] = fdot2(tt, h2(wd.z), gr[3]);
        }
#pragma unroll
        for (int j = 0; j < 5; ++j) gq[j] += bqg[j];
#pragma unroll
        for (int j = 0; j < 4; ++j) gr[j] += brg[j];

        const float ent0 = 7.0946927f + 0.5f * (gq[0] + gq[1] + gq[2] + gq[3] + gq[4]);
        const float logscale = fmaxf(7.1f - ent0, 0.0f) * 0.2f;
        const float entQ = fmaf(2.5f, logscale, ent0);
        const float entR = 5.6757541f + 0.5f * (gr[0] + gr[1] + gr[2] + gr[3]);
        float qd[5], rd[4];
#pragma unroll
        for (int j = 0; j < 5; ++j) qd[j] = fexp(gq[j] + logscale);
#pragma unroll
        for (int j = 0; j < 4; ++j) rd[j] = fexp(gr[j]);

#pragma unroll
        for (int j = 0; j < SD; ++j) Pp[IDX(j, j)] += qd[j];

        // ------- exact linear update: S = H5^T Pp H5 + R, Pxy = Pp H5 -------
        float Hh[7][4];
#pragma unroll
        for (int i = 0; i < 7; ++i)
#pragma unroll
            for (int m = 0; m < 4; ++m) Hh[i][m] = Hg[i * 4 + m];

        const float uu0 = Uin[bb * 2 + 0];
        const float uu1 = Uin[bb * 2 + 1];
        float yv[4];
#pragma unroll
        for (int m = 0; m < 4; ++m) yv[m] = Yin[bb * 4 + m];

        float yh[4];
#pragma unroll
        for (int m = 0; m < 4; ++m) {
            float v = fmaf(uu0, Hh[5][m], uu1 * Hh[6][m]);
#pragma unroll
            for (int i = 0; i < SD; ++i) v = fmaf(xp[i], Hh[i][m], v);
            yh[m] = v;
        }

        float Pxy[5][4];
#pragma unroll
        for (int i = 0; i < SD; ++i)
#pragma unroll
            for (int m = 0; m < 4; ++m) {
                float v = 0.0f;
#pragma unroll
                for (int j = 0; j < SD; ++j) {
                    float pij = (i >= j) ? Pp[IDX(i, j)] : Pp[IDX(j, i)];
                    v = fmaf(pij, Hh[j][m], v);
                }
                Pxy[i][m] = v;
            }

        float Sm[10];
#pragma unroll
        for (int m = 0; m < 4; ++m)
#pragma unroll
            for (int n = 0; n <= m; ++n) {
                float v = 0.0f;
#pragma unroll
                for (int i = 0; i < SD; ++i) v = fmaf(Hh[i][m], Pxy[i][n], v);
                Sm[IDX(m, n)] = v;
            }
#pragma unroll
        for (int m = 0; m < 4; ++m) Sm[IDX(m, m)] += rd[m];

        // Cholesky of S (4x4, packed lower)
        float Ls[10], di[4];
#pragma unroll
        for (int m = 0; m < 4; ++m) {
            float d = Sm[IDX(m, m)];
#pragma unroll
            for (int k = 0; k < m; ++k) { float l = Ls[IDX(m, k)]; d = fmaf(-l, l, d); }
            d = sqrtf(d);
            Ls[IDX(m, m)] = d;
            di[m] = 1.0f / d;
#pragma unroll
            for (int n = m + 1; n < 4; ++n) {
                float v = Sm[IDX(n, m)];
#pragma unroll
                for (int k = 0; k < m; ++k) v = fmaf(-Ls[IDX(n, k)], Ls[IDX(m, k)], v);
                Ls[IDX(n, m)] = v * di[m];
            }
        }

        // K = Pxy S^{-1}
        float K[5][4];
#pragma unroll
        for (int i = 0; i < SD; ++i) {
            float w[4];
#pragma unroll
            for (int m = 0; m < 4; ++m) {
                float v = Pxy[i][m];
#pragma unroll
                for (int k = 0; k < m; ++k) v = fmaf(-Ls[IDX(m, k)], w[k], v);
                w[m] = v * di[m];
            }
#pragma unroll
            for (int m = 3; m >= 0; --m) {
                float v = w[m];
#pragma unroll
                for (int k = m + 1; k < 4; ++k) v = fmaf(-Ls[IDX(k, m)], K[i][k], v);
                K[i][m] = v * di[m];
            }
        }

        float inn[4];
#pragma unroll
        for (int m = 0; m < 4; ++m) inn[m] = yv[m] - yh[m];

        float Xn[5];
#pragma unroll
        for (int i = 0; i < SD; ++i) {
            float v = xp[i];
#pragma unroll
            for (int m = 0; m < 4; ++m) v = fmaf(K[i][m], inn[m], v);
            Xn[i] = v;
        }

        // P_new = Pp - (K S) K^T
        float KS[5][4];
#pragma unroll
        for (int i = 0; i < SD; ++i)
#pragma unroll
            for (int m = 0; m < 4; ++m) {
                float v = 0.0f;
#pragma unroll
                for (int n = 0; n < 4; ++n) {
                    float snm = (n >= m) ? Sm[IDX(n, m)] : Sm[IDX(m, n)];
                    v = fmaf(K[i][n], snm, v);
                }
                KS[i][m] = v;
            }
        float Pn[15];
#pragma unroll
        for (int i = 0; i < SD; ++i)
#pragma unroll
            for (int j = 0; j <= i; ++j) {
                float v = Pp[IDX(i, j)];
#pragma unroll
                for (int m = 0; m < 4; ++m) v = fmaf(-KS[i][m], K[j][m], v);
                Pn[IDX(i, j)] = v;
            }

#pragma unroll
        for (int i = 0; i < SD; ++i) out[bb * SD + i] = Xn[i];
        float* Po = out + B_N * SD + bb * 25;
#pragma unroll
        for (int i = 0; i < SD; ++i)
#pragma unroll
            for (int j = 0; j < SD; ++j)
                Po[i * 5 + j] = (i >= j) ? Pn[IDX(i, j)] : Pn[IDX(j, i)];
        out[B_N * 30 + bb] = entQ;
        out[B_N * 31 + bb] = entR;
    }
}

extern "C" void kernel_launch(void* const* d_in, const int* in_sizes, int n_in,
                              void* d_out, int out_size, void* d_ws, size_t ws_size,
                              hipStream_t stream) {
    const float* Xh  = (const float*)d_in[0];
    const float* P   = (const float*)d_in[1];
    const float* u   = (const float*)d_in[2];
    const float* y   = (const float*)d_in[3];
    const float* W1  = (const float*)d_in[4];
    const float* b1  = (const float*)d_in[5];
    const float* W2  = (const float*)d_in[6];
    const float* b2  = (const float*)d_in[7];
    const float* Wn1 = (const float*)d_in[8];
    const float* bn1 = (const float*)d_in[9];
    const float* Wq  = (const float*)d_in[10];
    const float* bq  = (const float*)d_in[11];
    const float* Wr  = (const float*)d_in[12];
    const float* br  = (const float*)d_in[13];
    const float* Hob = (const float*)d_in[14];

    float* wpk = (float*)d_ws;           // 64 pairs * 16 floats = 4 KB
    float* wnk = wpk + 64 * 16;          // 32 pairs * 16 floats = 2 KB

    ukf_prep<<<1, 128, 0, stream>>>(W1, b1, W2, Wn1, bn1, Wq, Wr, wpk, wnk);
    ukf_main<<<B_N / 64, 704, 0, stream>>>(Xh, P, u, y, b2, bq, br, Hob,
                                           wpk, wnk, (float*)d_out);
}

// Round 6
// 167.563 us; speedup vs baseline: 1.0884x; 1.0884x over previous
//
#include <hip/hip_runtime.h>
#include <math.h>

#define B_N   32768
#define SD    5
#define MD    4
#define HID   128
#define NH    64
#define NSIG  11
#define DT    0.01f

#define IDX(i, j) ((i) * ((i) + 1) / 2 + (j))

typedef _Float16 h2v  __attribute__((ext_vector_type(2)));
typedef float    f32x4 __attribute__((ext_vector_type(4)));

#define CONST_AS __attribute__((address_space(4)))

// wave-uniform scalar load path (s_load_dwordx4)
__device__ __forceinline__ f32x4 ldc4(const float* p) {
    return *(const CONST_AS f32x4*)(uintptr_t)p;
}

__device__ __forceinline__ float fexp2(float x) {
#if __has_builtin(__builtin_amdgcn_exp2f)
    return __builtin_amdgcn_exp2f(x);
#else
    return exp2f(x);
#endif
}

__device__ __forceinline__ float fexp(float x) {
    return fexp2(x * 1.4426950408889634f);
}

// bitcast float <-> packed half2
__device__ __forceinline__ h2v h2b(float f) {
    union { float f; h2v h; } u; u.f = f; return u.h;
}
__device__ __forceinline__ float packh2(float a, float b) {
    union { h2v h; float f; } u;
    u.h.x = (_Float16)a; u.h.y = (_Float16)b;
    return u.f;
}

#define FMA2(a, b, c) __builtin_elementwise_fma((a), (b), (c))

// f32 odd order-9 polynomial tanh, clamped to [-3,3] (noise MLP path)
__device__ __forceinline__ float tpoly(float x) {
#if __has_builtin(__builtin_amdgcn_fmed3f)
    float p = __builtin_amdgcn_fmed3f(x, -3.0f, 3.0f);
#else
    float p = fminf(fmaxf(x, -3.0f), 3.0f);
#endif
    float u = p * p;
    float h = fmaf(u, 0.000412619f, -0.00901606f);
    h = fmaf(u, h, 0.07293188f);
    h = fmaf(u, h, -0.30093534f);
    h = fmaf(u, h, 0.9982018f);
    return p * h;
}

// ---- prep ----
// wpk: 64 pair-rows x 16 floats (each float = packed half2 over units k0=2p,k1=2p+1):
//   [0..6]  = (W1[i][k0], W1[i][k1])  i=0..6
//   [7]     = (b1[k0], b1[k1])
//   [8..14] = (W2[k0][j], W2[k1][j])  j=0..6
// wnk: 64 unit-rows x 16 floats (plain f32):
//   [0..4]=Wn1[i][k], [5]=bn1[k], [6..10]=Wq[k][j], [11..14]=Wr[k][j]
__global__ void ukf_prep(const float* __restrict__ W1, const float* __restrict__ b1,
                         const float* __restrict__ W2,
                         const float* __restrict__ Wn1, const float* __restrict__ bn1,
                         const float* __restrict__ Wq, const float* __restrict__ Wr,
                         float* __restrict__ wpk, float* __restrict__ wnk) {
    const int p = threadIdx.x;
    if (p < 64) {
        const int k0 = 2 * p, k1 = 2 * p + 1;
        float* o = wpk + p * 16;
#pragma unroll
        for (int i = 0; i < 7; ++i) o[i] = packh2(W1[i * HID + k0], W1[i * HID + k1]);
        o[7] = packh2(b1[k0], b1[k1]);
#pragma unroll
        for (int j = 0; j < 7; ++j) o[8 + j] = packh2(W2[k0 * 7 + j], W2[k1 * 7 + j]);
        o[15] = 0.0f;
    } else if (p < 128) {
        const int k = p - 64;
        float* o = wnk + k * 16;
#pragma unroll
        for (int i = 0; i < 5; ++i) o[i] = Wn1[i * NH + k];
        o[5] = bn1[k];
#pragma unroll
        for (int j = 0; j < 5; ++j) o[6 + j] = Wq[k * 5 + j];
#pragma unroll
        for (int j = 0; j < 4; ++j) o[11 + j] = Wr[k * 4 + j];
        o[15] = 0.0f;
    }
}

// MLP dynamics, packed-f16 (v_pk_fma_f16 / v_pk_mul_f16 / v_pk_max/min_f16).
// Two hidden units per iteration; weights via wave-uniform s_load.
__device__ __forceinline__ void dyn_eval(const float* __restrict__ wpk,
                                         const float* __restrict__ b2r,
                                         const float* __restrict__ z,
                                         float* __restrict__ out) {
    h2v zb[7];
#pragma unroll
    for (int i = 0; i < 7; ++i) { zb[i].x = (_Float16)z[i]; zb[i].y = zb[i].x; }

    const h2v PHI = { (_Float16)3.0f,          (_Float16)3.0f };
    const h2v PLO = { (_Float16)-3.0f,         (_Float16)-3.0f };
    const h2v C4  = { (_Float16)0.000412619f,  (_Float16)0.000412619f };
    const h2v C3  = { (_Float16)-0.00901606f,  (_Float16)-0.00901606f };
    const h2v C2  = { (_Float16)0.07293188f,   (_Float16)0.07293188f };
    const h2v C1  = { (_Float16)-0.30093534f,  (_Float16)-0.30093534f };
    const h2v C0  = { (_Float16)0.9982018f,    (_Float16)0.9982018f };

    h2v acc[7];
#pragma unroll
    for (int j = 0; j < 7; ++j) { acc[j].x = (_Float16)0.0f; acc[j].y = (_Float16)0.0f; }

#pragma unroll 4
    for (int p = 0; p < 64; ++p) {
        const float* row = wpk + (p << 4);
        f32x4 wa = ldc4(row);
        f32x4 wb = ldc4(row + 4);
        f32x4 wc = ldc4(row + 8);
        f32x4 wd = ldc4(row + 12);
        h2v pre = h2b(wb.w);                       // (b1[k0], b1[k1])
        pre = FMA2(zb[0], h2b(wa.x), pre);
        pre = FMA2(zb[1], h2b(wa.y), pre);
        pre = FMA2(zb[2], h2b(wa.z), pre);
        pre = FMA2(zb[3], h2b(wa.w), pre);
        pre = FMA2(zb[4], h2b(wb.x), pre);
        pre = FMA2(zb[5], h2b(wb.y), pre);
        pre = FMA2(zb[6], h2b(wb.z), pre);
        // packed poly tanh
        h2v pc = __builtin_elementwise_min(__builtin_elementwise_max(pre, PLO), PHI);
        h2v u = pc * pc;
        h2v h = FMA2(u, C4, C3);
        h = FMA2(u, h, C2);
        h = FMA2(u, h, C1);
        h = FMA2(u, h, C0);
        h2v tt = pc * h;
        acc[0] = FMA2(tt, h2b(wc.x), acc[0]);
        acc[1] = FMA2(tt, h2b(wc.y), acc[1]);
        acc[2] = FMA2(tt, h2b(wc.z), acc[2]);
        acc[3] = FMA2(tt, h2b(wc.w), acc[3]);
        acc[4] = FMA2(tt, h2b(wd.x), acc[4]);
        acc[5] = FMA2(tt, h2b(wd.y), acc[5]);
        acc[6] = FMA2(tt, h2b(wd.z), acc[6]);
    }
#pragma unroll
    for (int j = 0; j < 7; ++j)
        out[j] = b2r[j] + (float)acc[j].x + (float)acc[j].y;
}

// single main kernel: block = 704 threads = 64 elements x 11 sigma points.
__global__ __launch_bounds__(704) void ukf_main(
    const float* __restrict__ Xh, const float* __restrict__ Pin,
    const float* __restrict__ Uin, const float* __restrict__ Yin,
    const float* __restrict__ b2g, const float* __restrict__ bqg,
    const float* __restrict__ brg, const float* __restrict__ Hg,
    const float* __restrict__ wpk, const float* __restrict__ wnk,
    float* __restrict__ out) {
    __shared__ float spts[64 * 55];   // [elem][sig][5]

    const int tid = threadIdx.x;
    const int e = tid / NSIG;
    const int s = tid - e * NSIG;
    const int b = blockIdx.x * 64 + e;

    float b2r[7];
#pragma unroll
    for (int j = 0; j < 7; ++j) b2r[j] = b2g[j];

    float x[SD];
#pragma unroll
    for (int i = 0; i < SD; ++i) x[i] = Xh[b * SD + i];
    const float u0 = Uin[b * 2 + 0];
    const float u1 = Uin[b * 2 + 1];

    // Cholesky of 3*P (packed lower), redundantly per sigma-thread
    float L[15];
#pragma unroll
    for (int i = 0; i < SD; ++i)
#pragma unroll
        for (int j = 0; j <= i; ++j)
            L[IDX(i, j)] = 3.0f * Pin[b * 25 + i * 5 + j];
#pragma unroll
    for (int j = 0; j < SD; ++j) {
        float d = L[IDX(j, j)];
#pragma unroll
        for (int k = 0; k < j; ++k) { float l = L[IDX(j, k)]; d = fmaf(-l, l, d); }
        d = sqrtf(d);
        L[IDX(j, j)] = d;
        float inv = 1.0f / d;
#pragma unroll
        for (int i = j + 1; i < SD; ++i) {
            float v = L[IDX(i, j)];
#pragma unroll
            for (int k = 0; k < j; ++k) v = fmaf(-L[IDX(i, k)], L[IDX(j, k)], v);
            L[IDX(i, j)] = v * inv;
        }
    }

    float z[7];
#pragma unroll
    for (int i = 0; i < SD; ++i) z[i] = x[i];
    z[5] = u0; z[6] = u1;
    {
        const int c = (s >= 6) ? (s - 6) : (s - 1);   // -1 when s==0
        const float sgn = (s >= 6) ? -1.0f : 1.0f;
#pragma unroll
        for (int cc = 0; cc < SD; ++cc) {
            if (cc == c) {
#pragma unroll
                for (int i = cc; i < SD; ++i) z[i] = fmaf(sgn, L[IDX(i, cc)], z[i]);
            }
        }
    }

    float kc[7], ks[7], zc[7];
    dyn_eval(wpk, b2r, z, kc);                         // k1
#pragma unroll
    for (int i = 0; i < 7; ++i) { ks[i] = kc[i]; zc[i] = fmaf(0.5f * DT, kc[i], z[i]); }
    dyn_eval(wpk, b2r, zc, kc);                        // k2
#pragma unroll
    for (int i = 0; i < 7; ++i) { ks[i] = fmaf(2.0f, kc[i], ks[i]); zc[i] = fmaf(0.5f * DT, kc[i], z[i]); }
    dyn_eval(wpk, b2r, zc, kc);                        // k3
#pragma unroll
    for (int i = 0; i < 7; ++i) { ks[i] = fmaf(2.0f, kc[i], ks[i]); zc[i] = fmaf(DT, kc[i], z[i]); }
    dyn_eval(wpk, b2r, zc, kc);                        // k4
#pragma unroll
    for (int i = 0; i < SD; ++i)
        spts[e * 55 + s * 5 + i] = fmaf(DT / 6.0f, ks[i] + kc[i], z[i]);

    __syncthreads();

    // ---------------- phase 2: one thread per element ----------------
    if (tid < 64) {
        const int bb = blockIdx.x * 64 + tid;

        float xp[SD], M[15];
#pragma unroll
        for (int i = 0; i < SD; ++i) xp[i] = 0.0f;
#pragma unroll
        for (int i = 0; i < 15; ++i) M[i] = 0.0f;
#pragma unroll
        for (int si = 0; si < NSIG; ++si) {
            const float w = (si == 0) ? (-2.0f / 3.0f) : (1.0f / 6.0f);
            float p[SD];
#pragma unroll
            for (int i = 0; i < SD; ++i) p[i] = spts[tid * 55 + si * 5 + i];
#pragma unroll
            for (int i = 0; i < SD; ++i) xp[i] = fmaf(w, p[i], xp[i]);
#pragma unroll
            for (int i = 0; i < SD; ++i)
#pragma unroll
                for (int j = 0; j <= i; ++j)
                    M[IDX(i, j)] = fmaf(w * p[i], p[j], M[IDX(i, j)]);
        }
        float Pp[15];
#pragma unroll
        for (int i = 0; i < SD; ++i)
#pragma unroll
            for (int j = 0; j <= i; ++j)
                Pp[IDX(i, j)] = fmaf(-xp[i], xp[j], M[IDX(i, j)]);

        // noise MLP on original X_hat (f32 fma + f32 poly; scalar weight loads)
        float xh[SD];
#pragma unroll
        for (int i = 0; i < SD; ++i) xh[i] = Xh[bb * SD + i];
        float gq[5] = {0.f, 0.f, 0.f, 0.f, 0.f};
        float gr[4] = {0.f, 0.f, 0.f, 0.f};
#pragma unroll 4
        for (int k = 0; k < NH; ++k) {
            const float* row = wnk + (k << 4);
            f32x4 wa = ldc4(row);
            f32x4 wb = ldc4(row + 4);
            f32x4 wc = ldc4(row + 8);
            f32x4 wd = ldc4(row + 12);
            float pre = wb.y;                       // bn1[k]
            pre = fmaf(xh[0], wa.x, pre);
            pre = fmaf(xh[1], wa.y, pre);
            pre = fmaf(xh[2], wa.z, pre);
            pre = fmaf(xh[3], wa.w, pre);
            pre = fmaf(xh[4], wb.x, pre);
            float t = tpoly(pre);
            gq[0] = fmaf(t, wb.z, gq[0]);
            gq[1] = fmaf(t, wb.w, gq[1]);
            gq[2] = fmaf(t, wc.x, gq[2]);
            gq[3] = fmaf(t, wc.y, gq[3]);
            gq[4] = fmaf(t, wc.z, gq[4]);
            gr[0] = fmaf(t, wc.w, gr[0]);
            gr[1] = fmaf(t, wd.x, gr[1]);
            gr[2] = fmaf(t, wd.y, gr[2]);
            gr[3] = fmaf(t, wd.z, gr[3]);
        }
#pragma unroll
        for (int j = 0; j < 5; ++j) gq[j] += bqg[j];
#pragma unroll
        for (int j = 0; j < 4; ++j) gr[j] += brg[j];

        const float ent0 = 7.0946927f + 0.5f * (gq[0] + gq[1] + gq[2] + gq[3] + gq[4]);
        const float logscale = fmaxf(7.1f - ent0, 0.0f) * 0.2f;
        const float entQ = fmaf(2.5f, logscale, ent0);
        const float entR = 5.6757541f + 0.5f * (gr[0] + gr[1] + gr[2] + gr[3]);
        float qd[5], rd[4];
#pragma unroll
        for (int j = 0; j < 5; ++j) qd[j] = fexp(gq[j] + logscale);
#pragma unroll
        for (int j = 0; j < 4; ++j) rd[j] = fexp(gr[j]);

#pragma unroll
        for (int j = 0; j < SD; ++j) Pp[IDX(j, j)] += qd[j];

        // ------- exact linear update: S = H5^T Pp H5 + R, Pxy = Pp H5 -------
        float Hh[7][4];
#pragma unroll
        for (int i = 0; i < 7; ++i)
#pragma unroll
            for (int m = 0; m < 4; ++m) Hh[i][m] = Hg[i * 4 + m];

        const float uu0 = Uin[bb * 2 + 0];
        const float uu1 = Uin[bb * 2 + 1];
        float yv[4];
#pragma unroll
        for (int m = 0; m < 4; ++m) yv[m] = Yin[bb * 4 + m];

        float yh[4];
#pragma unroll
        for (int m = 0; m < 4; ++m) {
            float v = fmaf(uu0, Hh[5][m], uu1 * Hh[6][m]);
#pragma unroll
            for (int i = 0; i < SD; ++i) v = fmaf(xp[i], Hh[i][m], v);
            yh[m] = v;
        }

        float Pxy[5][4];
#pragma unroll
        for (int i = 0; i < SD; ++i)
#pragma unroll
            for (int m = 0; m < 4; ++m) {
                float v = 0.0f;
#pragma unroll
                for (int j = 0; j < SD; ++j) {
                    float pij = (i >= j) ? Pp[IDX(i, j)] : Pp[IDX(j, i)];
                    v = fmaf(pij, Hh[j][m], v);
                }
                Pxy[i][m] = v;
            }

        float Sm[10];
#pragma unroll
        for (int m = 0; m < 4; ++m)
#pragma unroll
            for (int n = 0; n <= m; ++n) {
                float v = 0.0f;
#pragma unroll
                for (int i = 0; i < SD; ++i) v = fmaf(Hh[i][m], Pxy[i][n], v);
                Sm[IDX(m, n)] = v;
            }
#pragma unroll
        for (int m = 0; m < 4; ++m) Sm[IDX(m, m)] += rd[m];

        // Cholesky of S (4x4, packed lower)
        float Ls[10], di[4];
#pragma unroll
        for (int m = 0; m < 4; ++m) {
            float d = Sm[IDX(m, m)];
#pragma unroll
            for (int k = 0; k < m; ++k) { float l = Ls[IDX(m, k)]; d = fmaf(-l, l, d); }
            d = sqrtf(d);
            Ls[IDX(m, m)] = d;
            di[m] = 1.0f / d;
#pragma unroll
            for (int n = m + 1; n < 4; ++n) {
                float v = Sm[IDX(n, m)];
#pragma unroll
                for (int k = 0; k < m; ++k) v = fmaf(-Ls[IDX(n, k)], Ls[IDX(m, k)], v);
                Ls[IDX(n, m)] = v * di[m];
            }
        }

        // K = Pxy S^{-1}
        float K[5][4];
#pragma unroll
        for (int i = 0; i < SD; ++i) {
            float w[4];
#pragma unroll
            for (int m = 0; m < 4; ++m) {
                float v = Pxy[i][m];
#pragma unroll
                for (int k = 0; k < m; ++k) v = fmaf(-Ls[IDX(m, k)], w[k], v);
                w[m] = v * di[m];
            }
#pragma unroll
            for (int m = 3; m >= 0; --m) {
                float v = w[m];
#pragma unroll
                for (int k = m + 1; k < 4; ++k) v = fmaf(-Ls[IDX(k, m)], K[i][k], v);
                K[i][m] = v * di[m];
            }
        }

        float inn[4];
#pragma unroll
        for (int m = 0; m < 4; ++m) inn[m] = yv[m] - yh[m];

        float Xn[5];
#pragma unroll
        for (int i = 0; i < SD; ++i) {
            float v = xp[i];
#pragma unroll
            for (int m = 0; m < 4; ++m) v = fmaf(K[i][m], inn[m], v);
            Xn[i] = v;
        }

        // P_new = Pp - (K S) K^T
        float KS[5][4];
#pragma unroll
        for (int i = 0; i < SD; ++i)
#pragma unroll
            for (int m = 0; m < 4; ++m) {
                float v = 0.0f;
#pragma unroll
                for (int n = 0; n < 4; ++n) {
                    float snm = (n >= m) ? Sm[IDX(n, m)] : Sm[IDX(m, n)];
                    v = fmaf(K[i][n], snm, v);
                }
                KS[i][m] = v;
            }
        float Pn[15];
#pragma unroll
        for (int i = 0; i < SD; ++i)
#pragma unroll
            for (int j = 0; j <= i; ++j) {
                float v = Pp[IDX(i, j)];
#pragma unroll
                for (int m = 0; m < 4; ++m) v = fmaf(-KS[i][m], K[j][m], v);
                Pn[IDX(i, j)] = v;
            }

#pragma unroll
        for (int i = 0; i < SD; ++i) out[bb * SD + i] = Xn[i];
        float* Po = out + B_N * SD + bb * 25;
#pragma unroll
        for (int i = 0; i < SD; ++i)
#pragma unroll
            for (int j = 0; j < SD; ++j)
                Po[i * 5 + j] = (i >= j) ? Pn[IDX(i, j)] : Pn[IDX(j, i)];
        out[B_N * 30 + bb] = entQ;
        out[B_N * 31 + bb] = entR;
    }
}

extern "C" void kernel_launch(void* const* d_in, const int* in_sizes, int n_in,
                              void* d_out, int out_size, void* d_ws, size_t ws_size,
                              hipStream_t stream) {
    const float* Xh  = (const float*)d_in[0];
    const float* P   = (const float*)d_in[1];
    const float* u   = (const float*)d_in[2];
    const float* y   = (const float*)d_in[3];
    const float* W1  = (const float*)d_in[4];
    const float* b1  = (const float*)d_in[5];
    const float* W2  = (const float*)d_in[6];
    const float* b2  = (const float*)d_in[7];
    const float* Wn1 = (const float*)d_in[8];
    const float* bn1 = (const float*)d_in[9];
    const float* Wq  = (const float*)d_in[10];
    const float* bq  = (const float*)d_in[11];
    const float* Wr  = (const float*)d_in[12];
    const float* br  = (const float*)d_in[13];
    const float* Hob = (const float*)d_in[14];

    float* wpk = (float*)d_ws;           // 64 pair-rows * 16 floats = 4 KB
    float* wnk = wpk + 64 * 16;          // 64 unit-rows * 16 floats = 4 KB

    ukf_prep<<<1, 128, 0, stream>>>(W1, b1, W2, Wn1, bn1, Wq, Wr, wpk, wnk);
    ukf_main<<<B_N / 64, 704, 0, stream>>>(Xh, P, u, y, b2, bq, br, Hob,
                                           wpk, wnk, (float*)d_out);
}